// Round 4
// baseline (760.752 us; speedup 1.0000x reference)
//
#include <hip/hip_runtime.h>

#define BATCH 4
#define SEQ 2048
#define DMODEL 512
#define NHEAD 8
#define DHEAD 64
#define NEXP 8
#define DFF 2048
#define TOK (BATCH*SEQ)

typedef __attribute__((ext_vector_type(8))) short short8;
typedef __attribute__((ext_vector_type(8))) _Float16 half8;
typedef __attribute__((ext_vector_type(4))) float f32x4;
typedef unsigned short u16;

typedef const __attribute__((address_space(1))) void gvoid;
typedef __attribute__((address_space(3))) void lvoid;
__device__ __forceinline__ void gload16(const void* g, void* l){
  __builtin_amdgcn_global_load_lds((gvoid*)g, (lvoid*)l, 16, 0, 0);
}

__device__ inline f32x4 zero4(){ f32x4 z = {0.f,0.f,0.f,0.f}; return z; }
__device__ inline u16 f2bf(float f){ unsigned u; __builtin_memcpy(&u,&f,4); u = (u + 0x7fffu + ((u>>16)&1u)) >> 16; return (u16)u; }
__device__ inline unsigned pack2(_Float16 a, _Float16 b){
  unsigned short ua, ub; __builtin_memcpy(&ua,&a,2); __builtin_memcpy(&ub,&b,2);
  return (unsigned)ua | ((unsigned)ub<<16);
}

// ---------------- transpose + cast: W (R x C, f32) -> Wt (C x R) ----------------
__global__ __launch_bounds__(256) void k_tc_bf(const float* __restrict__ W, u16* __restrict__ Wt, int R, int C){
  __shared__ float tile[32][33];
  long e = blockIdx.z;
  const float* Wp = W + e*(long)R*C;
  u16* Op = Wt + e*(long)R*C;
  int c0 = blockIdx.x*32, r0 = blockIdx.y*32;
  int tx = threadIdx.x & 31, ty = threadIdx.x >> 5;
  #pragma unroll
  for (int i=0;i<4;i++){ int r = ty*4+i; tile[r][tx] = Wp[(long)(r0+r)*C + c0+tx]; }
  __syncthreads();
  #pragma unroll
  for (int i=0;i<4;i++){ int cc = ty*4+i; Op[(long)(c0+cc)*R + r0+tx] = f2bf(tile[tx][cc]); }
}

__global__ __launch_bounds__(256) void k_tc_split(const float* __restrict__ W, _Float16* __restrict__ H, _Float16* __restrict__ L, int R, int C){
  __shared__ float tile[32][33];
  int c0 = blockIdx.x*32, r0 = blockIdx.y*32;
  int tx = threadIdx.x & 31, ty = threadIdx.x >> 5;
  #pragma unroll
  for (int i=0;i<4;i++){ int r = ty*4+i; tile[r][tx] = W[(long)(r0+r)*C + c0+tx]; }
  __syncthreads();
  #pragma unroll
  for (int i=0;i<4;i++){
    int cc = ty*4+i;
    float v = tile[tx][cc];
    _Float16 hi = (_Float16)v;
    long o = (long)(c0+cc)*R + r0+tx;
    H[o] = hi; L[o] = (_Float16)(v - (float)hi);
  }
}

// ---------------- V transpose per head: vt[bh][d][s] = v[b][s][h*64+d] ----------------
__global__ __launch_bounds__(256) void k_vtrans(const _Float16* __restrict__ vh, const _Float16* __restrict__ vl,
                                                _Float16* __restrict__ vth, _Float16* __restrict__ vtl){
  __shared__ _Float16 t[32][33];
  int bh = blockIdx.z;
  int b = bh>>3, h = bh&7;
  int s0 = blockIdx.x*32, d0 = blockIdx.y*32;
  int tx = threadIdx.x & 31, ty = threadIdx.x >> 5;
  const _Float16* src = vh; _Float16* dst = vth;
  #pragma unroll
  for (int pass=0; pass<2; pass++){
    #pragma unroll
    for (int i=0;i<4;i++){
      int sl = ty*4+i;
      t[sl][tx] = src[((long)b*SEQ + s0+sl)*DMODEL + h*64 + d0 + tx];
    }
    __syncthreads();
    #pragma unroll
    for (int i=0;i<4;i++){
      int dl = ty*4+i;
      dst[((long)bh*64 + d0+dl)*SEQ + s0 + tx] = t[tx][dl];
    }
    __syncthreads();
    src = vl; dst = vtl;
  }
}

// ---------------- RMSNorm ----------------
__global__ __launch_bounds__(256) void k_rmsnorm_split(const float* __restrict__ x, const float* __restrict__ w,
                                                       _Float16* __restrict__ oh, _Float16* __restrict__ ol){
  int row = blockIdx.x*4 + (threadIdx.x>>6);
  int lane = threadIdx.x & 63;
  const float4* xr = (const float4*)(x + (long)row*DMODEL);
  float4 a = xr[lane*2], b = xr[lane*2+1];
  float ss = a.x*a.x+a.y*a.y+a.z*a.z+a.w*a.w + b.x*b.x+b.y*b.y+b.z*b.z+b.w*b.w;
  #pragma unroll
  for (int o=32;o;o>>=1) ss += __shfl_xor(ss, o);
  float sc = rsqrtf(ss*(1.0f/DMODEL) + 1e-5f);
  const float4* wr = (const float4*)w;
  float4 wa = wr[lane*2], wb = wr[lane*2+1];
  float v[8] = {a.x*sc*wa.x, a.y*sc*wa.y, a.z*sc*wa.z, a.w*sc*wa.w,
                b.x*sc*wb.x, b.y*sc*wb.y, b.z*sc*wb.z, b.w*sc*wb.w};
  half8 hv, lv;
  #pragma unroll
  for (int j=0;j<8;j++){ _Float16 hi = (_Float16)v[j]; hv[j] = hi; lv[j] = (_Float16)(v[j]-(float)hi); }
  long off = (long)row*DMODEL + lane*8;
  *(half8*)(oh + off) = hv;
  *(half8*)(ol + off) = lv;
}

__global__ __launch_bounds__(256) void k_rmsnorm_bf(const float* __restrict__ x, const float* __restrict__ w, u16* __restrict__ o){
  int row = blockIdx.x*4 + (threadIdx.x>>6);
  int lane = threadIdx.x & 63;
  const float4* xr = (const float4*)(x + (long)row*DMODEL);
  float4 a = xr[lane*2], b = xr[lane*2+1];
  float ss = a.x*a.x+a.y*a.y+a.z*a.z+a.w*a.w + b.x*b.x+b.y*b.y+b.z*b.z+b.w*b.w;
  #pragma unroll
  for (int ofs=32;ofs;ofs>>=1) ss += __shfl_xor(ss, ofs);
  float sc = rsqrtf(ss*(1.0f/DMODEL) + 1e-5f);
  const float4* wr = (const float4*)w;
  float4 wa = wr[lane*2], wb = wr[lane*2+1];
  short8 ov;
  ov[0]=(short)f2bf(a.x*sc*wa.x); ov[1]=(short)f2bf(a.y*sc*wa.y);
  ov[2]=(short)f2bf(a.z*sc*wa.z); ov[3]=(short)f2bf(a.w*sc*wa.w);
  ov[4]=(short)f2bf(b.x*sc*wb.x); ov[5]=(short)f2bf(b.y*sc*wb.y);
  ov[6]=(short)f2bf(b.z*sc*wb.z); ov[7]=(short)f2bf(b.w*sc*wb.w);
  *(short8*)(o + (long)row*DMODEL + lane*8) = ov;
}

// ---------------- RoPE cos/sin table ----------------
__global__ __launch_bounds__(256) void k_rope_tab(float2* __restrict__ tab){
  int idx = blockIdx.x*256 + threadIdx.x;
  int s = idx>>5, i = idx&31;
  float invf = powf(10000.0f, -(float)(2*i)*(1.0f/64.0f));
  float ang = (float)s * invf;
  tab[idx] = make_float2(cosf(ang), sinf(ang));
}

// ---------------- split-f16 GEMM (fp32 fidelity), gload_lds + 2-phase dbuf ----------------
template<int EPI>
__global__ __launch_bounds__(256) void k_gemm_split(
    const _Float16* __restrict__ Ah, const _Float16* __restrict__ Al,
    const _Float16* __restrict__ Bh, const _Float16* __restrict__ Bl,
    _Float16* __restrict__ oh, _Float16* __restrict__ ol,
    float* __restrict__ of1, float* __restrict__ of2,
    const float* __restrict__ extra, const float2* __restrict__ tab,
    int M, int N, int K)
{
  __shared__ _Float16 lAb[2*128*64];
  __shared__ _Float16 lBb[2*128*64];
  const int mb = blockIdx.x*128, nb = blockIdx.y*128;
  const int tid = threadIdx.x, lane = tid&63, wv = tid>>6;
  const int wr = wv>>1, wc = wv&1;
  const int fr = lane&15, fq = lane>>4;
  // staging: lane covers row (i*32+wv*8+(l>>3)), lds chunk (l&7); source chunk cs = (l&7)^(row&7)
  const int cs = (lane&7) ^ (lane>>3);
  const _Float16* pA[4]; const _Float16* pB[4];
  #pragma unroll
  for (int i=0;i<4;i++){
    int rr = i*32 + wv*8 + (lane>>3);
    const _Float16* a = (cs<4)? Ah : Al;
    const _Float16* b = (cs<4)? Bh : Bl;
    pA[i] = a + (long)(mb+rr)*K + (cs&3)*8;
    pB[i] = b + (long)(nb+rr)*K + (cs&3)*8;
  }
  f32x4 acc[4][4];
  #pragma unroll
  for (int mi=0;mi<4;mi++)
    #pragma unroll
    for (int ni=0;ni<4;ni++) acc[mi][ni] = zero4();

  #pragma unroll
  for (int i=0;i<4;i++){
    gload16(pA[i], (char*)lAb + (i*32+wv*8)*128);
    gload16(pB[i], (char*)lBb + (i*32+wv*8)*128);
  }
  __syncthreads();
  const int NT = K>>5;
  int cur = 0;
  for (int t=0; t<NT; ++t){
    if (t+1 < NT){
      int k2 = (t+1)<<5;
      #pragma unroll
      for (int i=0;i<4;i++){
        int db = ((cur^1)<<14) + (i*32+wv*8)*128;
        gload16(pA[i]+k2, (char*)lAb + db);
        gload16(pB[i]+k2, (char*)lBb + db);
      }
    }
    const char* cA = (const char*)lAb + (cur<<14);
    const char* cB = (const char*)lBb + (cur<<14);
    half8 ax[4], ay[4], bx[4], by[4];
    #pragma unroll
    for (int mi=0;mi<4;mi++){
      int row = wr*64 + mi*16 + fr; int m7 = row&7; const char* rb = cA + row*128;
      ax[mi] = *(const half8*)(rb + (((fq  ) ^ m7)<<4));
      ay[mi] = *(const half8*)(rb + (((fq+4) ^ m7)<<4));
    }
    #pragma unroll
    for (int ni=0;ni<4;ni++){
      int row = wc*64 + ni*16 + fr; int m7 = row&7; const char* rb = cB + row*128;
      bx[ni] = *(const half8*)(rb + (((fq  ) ^ m7)<<4));
      by[ni] = *(const half8*)(rb + (((fq+4) ^ m7)<<4));
    }
    __builtin_amdgcn_s_setprio(1);
    #pragma unroll
    for (int mi=0;mi<4;mi++)
      #pragma unroll
      for (int ni=0;ni<4;ni++){
        acc[mi][ni] = __builtin_amdgcn_mfma_f32_16x16x32_f16(ax[mi], bx[ni], acc[mi][ni], 0,0,0);
        acc[mi][ni] = __builtin_amdgcn_mfma_f32_16x16x32_f16(ax[mi], by[ni], acc[mi][ni], 0,0,0);
        acc[mi][ni] = __builtin_amdgcn_mfma_f32_16x16x32_f16(ay[mi], bx[ni], acc[mi][ni], 0,0,0);
      }
    __builtin_amdgcn_s_setprio(0);
    __syncthreads();
    cur ^= 1;
  }
  #pragma unroll
  for (int mi=0;mi<4;mi++)
    #pragma unroll
    for (int ni=0;ni<4;ni++)
      #pragma unroll
      for (int r=0;r<4;r++){
        int row = mb + wr*64 + mi*16 + fq*4 + r;
        int col = nb + wc*64 + ni*16 + fr;
        long off = (long)row*N + col;
        float v = acc[mi][ni][r];
        if (EPI==0){
          float v2 = __shfl_xor(v, 1);
          float2 csn = tab[(row & (SEQ-1))*32 + ((col&63)>>1)];
          float o = (col&1) ? (v2*csn.y + v*csn.x) : (v*csn.x - v2*csn.y);
          _Float16 hi = (_Float16)o;
          oh[off] = hi; ol[off] = (_Float16)(o - (float)hi);
        } else if (EPI==1){
          _Float16 hi = (_Float16)v;
          oh[off] = hi; ol[off] = (_Float16)(v - (float)hi);
        } else {
          float hv = extra[off] + v;
          of1[off] = hv; of2[off] = hv;
        }
      }
}

// ---------------- split-f16 causal flash attention (descending qt, exp2 softmax) ----------------
__global__ __launch_bounds__(256) void k_flash(
    const _Float16* __restrict__ Qh, const _Float16* __restrict__ Ql,
    const _Float16* __restrict__ Kh, const _Float16* __restrict__ Kl,
    const _Float16* __restrict__ Vth, const _Float16* __restrict__ Vtl,
    _Float16* __restrict__ Oh, _Float16* __restrict__ Ol)
{
  __shared__ _Float16 lK[64*128];
  __shared__ _Float16 lV[64*128];
  __shared__ _Float16 lP[4*2304];
  const int qt = (SEQ/64 - 1) - blockIdx.x;    // longest blocks launch first
  const int bh = blockIdx.y;
  const int b = bh>>3, hh = bh&7;
  const int tid = threadIdx.x, lane = tid&63, wid = tid>>6;
  const int fr = lane&15, fq = lane>>4;
  const long base = ((long)b*SEQ)*DMODEL + hh*DHEAD;
  const long vtb  = (long)bh*DHEAD*SEQ;
  const int srow = tid>>4, sch = tid&15;
  const unsigned pw = wid*2304;
  const float SCL = 0.18033688011112042f;      // 0.125 * log2(e)

  const int q0 = qt*64, qw = q0 + wid*16;
  half8 qfh[2], qfl[2];
  #pragma unroll
  for (int kk=0;kk<2;kk++){
    long o = base + (long)(qw+fr)*DMODEL + kk*32 + fq*8;
    qfh[kk] = *(const half8*)(Qh + o);
    qfl[kk] = *(const half8*)(Ql + o);
  }
  f32x4 oacc[4];
  #pragma unroll
  for (int i=0;i<4;i++) oacc[i] = zero4();
  float mrow[4], lrow[4];
  #pragma unroll
  for (int r=0;r<4;r++){ mrow[r] = -__builtin_inff(); lrow[r] = 0.f; }

  for (int kvt=0; kvt<=qt; kvt++){
    int k0 = kvt*64;
    half8 kreg[4], vreg[4];
    #pragma unroll
    for (int i=0;i<4;i++){
      int row = i*16 + srow;
      const _Float16* ks = (sch<8) ? Kh : Kl;
      kreg[i] = *(const half8*)(ks + base + (long)(k0+row)*DMODEL + (sch&7)*8);
      const _Float16* vs = (sch<8) ? Vth : Vtl;
      vreg[i] = *(const half8*)(vs + vtb + (long)row*SEQ + k0 + (sch&7)*8);
    }
    __syncthreads();
    #pragma unroll
    for (int i=0;i<4;i++){
      int row = i*16 + srow;
      int slot = ((sch ^ (row&15))<<4);
      *(half8*)((char*)lK + row*256 + slot) = kreg[i];
      *(half8*)((char*)lV + row*256 + slot) = vreg[i];
    }
    __syncthreads();
    // ---- scores
    f32x4 sc[4];
    __builtin_amdgcn_s_setprio(1);
    #pragma unroll
    for (int ns=0;ns<4;ns++){
      f32x4 a = zero4();
      #pragma unroll
      for (int kk=0;kk<2;kk++){
        int row = ns*16 + fr; int m15 = row&15; const char* rb = (const char*)lK + row*256;
        half8 kfh = *(const half8*)(rb + (((kk*4+fq)   ^ m15)<<4));
        half8 kfl = *(const half8*)(rb + (((kk*4+fq+8) ^ m15)<<4));
        a = __builtin_amdgcn_mfma_f32_16x16x32_f16(qfh[kk], kfh, a, 0,0,0);
        a = __builtin_amdgcn_mfma_f32_16x16x32_f16(qfh[kk], kfl, a, 0,0,0);
        a = __builtin_amdgcn_mfma_f32_16x16x32_f16(qfl[kk], kfh, a, 0,0,0);
      }
      sc[ns] = a;
    }
    __builtin_amdgcn_s_setprio(0);
    // ---- scale to exp2 base; mask only on diagonal tile
    float pmax[4];
    #pragma unroll
    for (int r=0;r<4;r++) pmax[r] = -__builtin_inff();
    if (kvt == qt){
      #pragma unroll
      for (int ns=0;ns<4;ns++)
        #pragma unroll
        for (int r=0;r<4;r++){
          int kvp = k0 + ns*16 + fr;
          int qp  = qw + fq*4 + r;
          float s = sc[ns][r]*SCL;
          if (kvp > qp) s = -1e30f;
          sc[ns][r] = s;
          pmax[r] = fmaxf(pmax[r], s);
        }
    } else {
      #pragma unroll
      for (int ns=0;ns<4;ns++)
        #pragma unroll
        for (int r=0;r<4;r++){
          float s = sc[ns][r]*SCL;
          sc[ns][r] = s;
          pmax[r] = fmaxf(pmax[r], s);
        }
    }
    #pragma unroll
    for (int o=1;o<16;o<<=1)
      #pragma unroll
      for (int r=0;r<4;r++) pmax[r] = fmaxf(pmax[r], __shfl_xor(pmax[r], o));
    // ---- defer-max: rescale only when the running max grew by >10 (log2 units)
    bool need = false;
    #pragma unroll
    for (int r=0;r<4;r++) need = need || (pmax[r] > mrow[r] + 10.f);
    if (__any(need)){
      float sf[4];
      #pragma unroll
      for (int r=0;r<4;r++){
        float mn = fmaxf(mrow[r], pmax[r]);
        sf[r] = exp2f(mrow[r]-mn);
        mrow[r] = mn;
        lrow[r] *= sf[r];
      }
      #pragma unroll
      for (int dt=0;dt<4;dt++)
        #pragma unroll
        for (int r=0;r<4;r++) oacc[dt][r] *= sf[r];
    }
    // ---- exp2 + P pair-store (even lanes -> hi plane, odd lanes -> lo plane)
    float rsum[4] = {0,0,0,0};
    #pragma unroll
    for (int ns=0;ns<4;ns++)
      #pragma unroll
      for (int r=0;r<4;r++){
        float pv = exp2f(sc[ns][r]-mrow[r]);
        rsum[r] += pv;
        float pv2 = __shfl_xor(pv, 1);
        float e0 = (fr&1)? pv2 : pv;
        float e1 = (fr&1)? pv : pv2;
        _Float16 f0 = (_Float16)e0, f1 = (_Float16)e1;
        unsigned word;
        if (fr&1) word = pack2((_Float16)(e0-(float)f0), (_Float16)(e1-(float)f1));
        else      word = pack2(f0, f1);
        unsigned eo = pw + ((fr&1)? 1152u:0u) + (unsigned)((fq*4+r)*72 + ns*16 + (fr&~1));
        *(unsigned*)((char*)lP + eo*2) = word;
      }
    #pragma unroll
    for (int o=1;o<16;o<<=1)
      #pragma unroll
      for (int r=0;r<4;r++) rsum[r] += __shfl_xor(rsum[r], o);
    #pragma unroll
    for (int r=0;r<4;r++) lrow[r] += rsum[r];
    // ---- PV (wave-local P; no barrier needed)
    __builtin_amdgcn_s_setprio(1);
    #pragma unroll
    for (int kk=0;kk<2;kk++){
      const char* pb = (const char*)lP + (pw + (unsigned)(fr*72 + kk*32))*2;
      half8 pfh = *(const half8*)(pb + fq*16);
      half8 pfl = *(const half8*)(pb + 2304 + fq*16);
      #pragma unroll
      for (int dt=0;dt<4;dt++){
        int row = dt*16 + fr; int m15 = row&15; const char* vb = (const char*)lV + row*256;
        half8 vfh = *(const half8*)(vb + (((kk*4+fq)   ^ m15)<<4));
        half8 vfl = *(const half8*)(vb + (((kk*4+fq+8) ^ m15)<<4));
        oacc[dt] = __builtin_amdgcn_mfma_f32_16x16x32_f16(pfh, vfh, oacc[dt], 0,0,0);
        oacc[dt] = __builtin_amdgcn_mfma_f32_16x16x32_f16(pfh, vfl, oacc[dt], 0,0,0);
        oacc[dt] = __builtin_amdgcn_mfma_f32_16x16x32_f16(pfl, vfh, oacc[dt], 0,0,0);
      }
    }
    __builtin_amdgcn_s_setprio(0);
  }
  #pragma unroll
  for (int dt=0;dt<4;dt++)
    #pragma unroll
    for (int r=0;r<4;r++){
      int qp = qw + fq*4 + r;
      float ov = oacc[dt][r] / lrow[r];
      long o = base + (long)qp*DMODEL + dt*16 + fr;
      _Float16 hi = (_Float16)ov;
      Oh[o] = hi; Ol[o] = (_Float16)(ov - (float)hi);
    }
}

// ---------------- router: fp32 RMSNorm + logits + softmax + top2 (no atomics) ----------------
__global__ __launch_bounds__(256) void k_router(const float* __restrict__ h, const float* __restrict__ w,
                                                const float* __restrict__ rw, float* __restrict__ gates,
                                                unsigned* __restrict__ choice){
  int tok = blockIdx.x*4 + (threadIdx.x>>6);
  int lane = threadIdx.x & 63;
  const float4* xr = (const float4*)(h + (long)tok*DMODEL);
  float4 a = xr[lane*2], b = xr[lane*2+1];
  float ss = a.x*a.x+a.y*a.y+a.z*a.z+a.w*a.w + b.x*b.x+b.y*b.y+b.z*b.z+b.w*b.w;
  #pragma unroll
  for (int o=32;o;o>>=1) ss += __shfl_xor(ss, o);
  float sc = rsqrtf(ss*(1.0f/DMODEL) + 1e-5f);
  const float4* wr = (const float4*)w;
  float4 wa = wr[lane*2], wb = wr[lane*2+1];
  float xv[8] = {a.x*sc*wa.x, a.y*sc*wa.y, a.z*sc*wa.z, a.w*sc*wa.w,
                 b.x*sc*wb.x, b.y*sc*wb.y, b.z*sc*wb.z, b.w*sc*wb.w};
  float lg[8] = {0,0,0,0,0,0,0,0};
  #pragma unroll
  for (int j=0;j<8;j++){
    const float* rp = rw + (long)(lane*8+j)*NEXP;
    #pragma unroll
    for (int e=0;e<8;e++) lg[e] += xv[j]*rp[e];
  }
  #pragma unroll
  for (int o=1;o<64;o<<=1)
    #pragma unroll
    for (int e=0;e<8;e++) lg[e] += __shfl_xor(lg[e], o);
  float mx = lg[0];
  #pragma unroll
  for (int e=1;e<8;e++) mx = fmaxf(mx, lg[e]);
  float pe[8], sm = 0.f;
  #pragma unroll
  for (int e=0;e<8;e++){ pe[e] = expf(lg[e]-mx); sm += pe[e]; }
  #pragma unroll
  for (int e=0;e<8;e++) pe[e] /= sm;
  int e1 = 0; float p1 = pe[0];
  #pragma unroll
  for (int e=1;e<8;e++) if (pe[e] > p1){ p1 = pe[e]; e1 = e; }
  int e2 = -1; float p2 = -1.f;
  #pragma unroll
  for (int e=0;e<8;e++) if (e != e1 && pe[e] > p2){ p2 = pe[e]; e2 = e; }
  float gs = p1 + p2;
  if (lane == 0){
    #pragma unroll
    for (int e=0;e<8;e++)
      gates[(long)tok*NEXP + e] = (e==e1) ? (p1/gs) : ((e==e2) ? (p2/gs) : 0.f);
    choice[tok] = (unsigned)e1 | ((unsigned)e2<<8);
  }
}

// ---------------- build expert lists: block-local counting sort ----------------
__global__ __launch_bounds__(256) void k_build(const unsigned* __restrict__ choice,
                                               int* __restrict__ cnt, int* __restrict__ perm){
  __shared__ int lcnt[NEXP];
  __shared__ int lbase[NEXP];
  const int tid = threadIdx.x;
  const int tok = blockIdx.x*256 + tid;
  if (tid < NEXP) lcnt[tid] = 0;
  __syncthreads();
  unsigned ch = choice[tok];
  int e1 = ch & 0xff, e2 = (ch>>8) & 0xff;
  int p1 = atomicAdd(&lcnt[e1], 1);
  int p2 = atomicAdd(&lcnt[e2], 1);
  __syncthreads();
  if (tid < NEXP) lbase[tid] = atomicAdd(&cnt[tid], lcnt[tid]);
  __syncthreads();
  perm[e1*TOK + lbase[e1] + p1] = tok;
  perm[e2*TOK + lbase[e2] + p2] = tok;
}

__global__ void k_prefix(const int* __restrict__ cnt, int* __restrict__ baseP){
  if (threadIdx.x==0 && blockIdx.x==0){
    int run = 0;
    for (int e=0;e<NEXP;e++){ baseP[e] = run; run += (cnt[e]+127) & ~127; }
  }
}

// ---------------- sparse MoE layer 1: gathered A via gload_lds, GELU -> compact mid ----------------
__global__ __launch_bounds__(256) void k_moe1(
    const u16* __restrict__ A, const u16* __restrict__ W1, u16* __restrict__ mid,
    const int* __restrict__ perm, const int* __restrict__ cnt, const int* __restrict__ baseP)
{
  const int e = blockIdx.z;
  const int ce = cnt[e];
  const int mb = blockIdx.x*128;
  if (mb >= ce) return;
  const int bp = baseP[e];
  const u16* Bt = W1 + (size_t)e*DFF*DMODEL;
  const int nb = blockIdx.y*128;
  __shared__ u16 lA[128*64];
  __shared__ u16 lB[128*64];
  const int tid = threadIdx.x, lane = tid&63, wv = tid>>6;
  const int wr = wv>>1, wc = wv&1;
  const int fr = lane&15, fq = lane>>4;
  const int cs = (lane&7) ^ (lane>>3);
  const u16* pA[4]; const u16* pB[4];
  #pragma unroll
  for (int i=0;i<4;i++){
    int rr = mb + i*32 + wv*8 + (lane>>3);
    int tok = perm[e*TOK + (rr < ce ? rr : ce-1)];
    pA[i] = A  + (long)tok*DMODEL + cs*8;
    pB[i] = Bt + (long)(nb + i*32 + wv*8 + (lane>>3))*DMODEL + cs*8;
  }
  f32x4 acc[4][4];
  #pragma unroll
  for (int mi=0;mi<4;mi++)
    #pragma unroll
    for (int ni=0;ni<4;ni++) acc[mi][ni] = zero4();

  for (int kt=0; kt<DMODEL; kt+=64){
    #pragma unroll
    for (int i=0;i<4;i++){
      gload16(pA[i]+kt, (char*)lA + (i*32+wv*8)*128);
      gload16(pB[i]+kt, (char*)lB + (i*32+wv*8)*128);
    }
    __syncthreads();
    __builtin_amdgcn_s_setprio(1);
    #pragma unroll
    for (int kk=0;kk<2;kk++){
      short8 af[4], bff[4];
      #pragma unroll
      for (int mi=0;mi<4;mi++){
        int row = wr*64 + mi*16 + fr;
        af[mi] = *(const short8*)((char*)lA + row*128 + (((kk*4+fq) ^ (row&7))<<4));
      }
      #pragma unroll
      for (int ni=0;ni<4;ni++){
        int row = wc*64 + ni*16 + fr;
        bff[ni] = *(const short8*)((char*)lB + row*128 + (((kk*4+fq) ^ (row&7))<<4));
      }
      #pragma unroll
      for (int mi=0;mi<4;mi++)
        #pragma unroll
        for (int ni=0;ni<4;ni++)
          acc[mi][ni] = __builtin_amdgcn_mfma_f32_16x16x32_bf16(af[mi], bff[ni], acc[mi][ni], 0,0,0);
    }
    __builtin_amdgcn_s_setprio(0);
    __syncthreads();
  }
  #pragma unroll
  for (int mi=0;mi<4;mi++)
    #pragma unroll
    for (int ni=0;ni<4;ni++)
      #pragma unroll
      for (int r=0;r<4;r++){
        int row_loc = mb + wr*64 + mi*16 + fq*4 + r;
        int col = nb + wc*64 + ni*16 + fr;
        float v = acc[mi][ni][r];
        mid[(size_t)(bp + row_loc)*DFF + col] = f2bf(0.5f*v*(1.f + erff(v*0.7071067811865475f)));
      }
}

// ---------------- sparse MoE layer 2: gload_lds, gated atomic scatter ----------------
__global__ __launch_bounds__(256) void k_moe2(
    const u16* __restrict__ mid, const u16* __restrict__ W2, float* __restrict__ out,
    const int* __restrict__ perm, const int* __restrict__ cnt, const int* __restrict__ baseP,
    const float* __restrict__ gates)
{
  const int e = blockIdx.z;
  const int ce = cnt[e];
  const int mb = blockIdx.x*128;
  if (mb >= ce) return;
  const int bp = baseP[e];
  const u16* Bt = W2 + (size_t)e*DMODEL*DFF;
  const int nb = blockIdx.y*128;
  __shared__ u16 lA[128*64];
  __shared__ u16 lB[128*64];
  const int tid = threadIdx.x, lane = tid&63, wv = tid>>6;
  const int wr = wv>>1, wc = wv&1;
  const int fr = lane&15, fq = lane>>4;
  const int cs = (lane&7) ^ (lane>>3);
  const u16* pA[4]; const u16* pB[4];
  #pragma unroll
  for (int i=0;i<4;i++){
    int rr = i*32 + wv*8 + (lane>>3);
    pA[i] = mid + (size_t)(bp + mb + rr)*DFF + cs*8;
    pB[i] = Bt  + (long)(nb + rr)*DFF + cs*8;
  }
  f32x4 acc[4][4];
  #pragma unroll
  for (int mi=0;mi<4;mi++)
    #pragma unroll
    for (int ni=0;ni<4;ni++) acc[mi][ni] = zero4();

  for (int kt=0; kt<DFF; kt+=64){
    #pragma unroll
    for (int i=0;i<4;i++){
      gload16(pA[i]+kt, (char*)lA + (i*32+wv*8)*128);
      gload16(pB[i]+kt, (char*)lB + (i*32+wv*8)*128);
    }
    __syncthreads();
    __builtin_amdgcn_s_setprio(1);
    #pragma unroll
    for (int kk=0;kk<2;kk++){
      short8 af[4], bff[4];
      #pragma unroll
      for (int mi=0;mi<4;mi++){
        int row = wr*64 + mi*16 + fr;
        af[mi] = *(const short8*)((char*)lA + row*128 + (((kk*4+fq) ^ (row&7))<<4));
      }
      #pragma unroll
      for (int ni=0;ni<4;ni++){
        int row = wc*64 + ni*16 + fr;
        bff[ni] = *(const short8*)((char*)lB + row*128 + (((kk*4+fq) ^ (row&7))<<4));
      }
      #pragma unroll
      for (int mi=0;mi<4;mi++)
        #pragma unroll
        for (int ni=0;ni<4;ni++)
          acc[mi][ni] = __builtin_amdgcn_mfma_f32_16x16x32_bf16(af[mi], bff[ni], acc[mi][ni], 0,0,0);
    }
    __builtin_amdgcn_s_setprio(0);
    __syncthreads();
  }
  #pragma unroll
  for (int mi=0;mi<4;mi++)
    #pragma unroll
    for (int ni=0;ni<4;ni++)
      #pragma unroll
      for (int r=0;r<4;r++){
        int row_loc = mb + wr*64 + mi*16 + fq*4 + r;
        if (row_loc < ce){
          int tok = perm[e*TOK + row_loc];
          int col = nb + wc*64 + ni*16 + fr;
          float g = gates[(long)tok*NEXP + e];
          atomicAdd(out + (long)tok*DMODEL + col, g*acc[mi][ni][r]);
        }
      }
}

// ---------------- launch ----------------
extern "C" void kernel_launch(void* const* d_in, const int* in_sizes, int n_in,
                              void* d_out, int out_size, void* d_ws, size_t ws_size,
                              hipStream_t stream)
{
  const float* x   = (const float*)d_in[0];
  const float* anw = (const float*)d_in[1];
  const float* wq  = (const float*)d_in[2];
  const float* wk  = (const float*)d_in[3];
  const float* wv  = (const float*)d_in[4];
  const float* wo  = (const float*)d_in[5];
  const float* fnw = (const float*)d_in[6];
  const float* rw  = (const float*)d_in[7];
  const float* w1  = (const float*)d_in[8];
  const float* w2  = (const float*)d_in[9];
  float* out = (float*)d_out;

  char* p = (char*)d_ws;
  auto alloc = [&](size_t n){ char* r = p; p += (n + 255) & ~(size_t)255; return r; };
  // region A (80MB): dead after flash; reused as compact MoE mid buffer (68MB needed)
  _Float16* xnh = (_Float16*)alloc((size_t)TOK*DMODEL*2);
  _Float16* xnl = (_Float16*)alloc((size_t)TOK*DMODEL*2);
  _Float16* qh  = (_Float16*)alloc((size_t)TOK*DMODEL*2);
  _Float16* ql  = (_Float16*)alloc((size_t)TOK*DMODEL*2);
  _Float16* kh  = (_Float16*)alloc((size_t)TOK*DMODEL*2);
  _Float16* kl  = (_Float16*)alloc((size_t)TOK*DMODEL*2);
  _Float16* vh  = (_Float16*)alloc((size_t)TOK*DMODEL*2);
  _Float16* vl  = (_Float16*)alloc((size_t)TOK*DMODEL*2);
  _Float16* vth = (_Float16*)alloc((size_t)TOK*DMODEL*2);
  _Float16* vtl = (_Float16*)alloc((size_t)TOK*DMODEL*2);
  u16* hmid = (u16*)xnh;   // alias region A
  // persistent
  _Float16* wqTh = (_Float16*)alloc((size_t)DMODEL*DMODEL*2);
  _Float16* wqTl = (_Float16*)alloc((size_t)DMODEL*DMODEL*2);
  _Float16* wkTh = (_Float16*)alloc((size_t)DMODEL*DMODEL*2);
  _Float16* wkTl = (_Float16*)alloc((size_t)DMODEL*DMODEL*2);
  _Float16* wvTh = (_Float16*)alloc((size_t)DMODEL*DMODEL*2);
  _Float16* wvTl = (_Float16*)alloc((size_t)DMODEL*DMODEL*2);
  _Float16* woTh = (_Float16*)alloc((size_t)DMODEL*DMODEL*2);
  _Float16* woTl = (_Float16*)alloc((size_t)DMODEL*DMODEL*2);
  u16* w1T = (u16*)alloc((size_t)NEXP*DFF*DMODEL*2);
  u16* w2T = (u16*)alloc((size_t)NEXP*DMODEL*DFF*2);
  _Float16* aoh = (_Float16*)alloc((size_t)TOK*DMODEL*2);
  _Float16* aol = (_Float16*)alloc((size_t)TOK*DMODEL*2);
  float* hb  = (float*)alloc((size_t)TOK*DMODEL*4);
  u16* hnb   = (u16*)alloc((size_t)TOK*DMODEL*2);
  float2* tab = (float2*)alloc((size_t)SEQ*32*sizeof(float2));
  float* gates = (float*)alloc((size_t)TOK*NEXP*4);
  int* perm  = (int*)alloc((size_t)NEXP*TOK*4);
  unsigned* choice = (unsigned*)alloc((size_t)TOK*4);
  int* cnt   = (int*)alloc(64*4);
  int* baseP = (int*)alloc(64*4);

  dim3 blk(256);
  hipMemsetAsync(cnt, 0, NEXP*sizeof(int), stream);
  // weight prep
  k_tc_split<<<dim3(16,16,1), blk, 0, stream>>>(wq, wqTh, wqTl, DMODEL, DMODEL);
  k_tc_split<<<dim3(16,16,1), blk, 0, stream>>>(wk, wkTh, wkTl, DMODEL, DMODEL);
  k_tc_split<<<dim3(16,16,1), blk, 0, stream>>>(wv, wvTh, wvTl, DMODEL, DMODEL);
  k_tc_split<<<dim3(16,16,1), blk, 0, stream>>>(wo, woTh, woTl, DMODEL, DMODEL);
  k_tc_bf<<<dim3(DFF/32, DMODEL/32, NEXP), blk, 0, stream>>>(w1, w1T, DMODEL, DFF);
  k_tc_bf<<<dim3(DMODEL/32, DFF/32, NEXP), blk, 0, stream>>>(w2, w2T, DFF, DMODEL);
  k_rope_tab<<<dim3(SEQ*32/256), blk, 0, stream>>>(tab);
  // attention path (split f16)
  k_rmsnorm_split<<<dim3(TOK/4), blk, 0, stream>>>(x, anw, xnh, xnl);
  k_gemm_split<0><<<dim3(TOK/128, DMODEL/128), blk, 0, stream>>>(xnh, xnl, wqTh, wqTl, qh, ql, nullptr, nullptr, nullptr, tab, TOK, DMODEL, DMODEL);
  k_gemm_split<0><<<dim3(TOK/128, DMODEL/128), blk, 0, stream>>>(xnh, xnl, wkTh, wkTl, kh, kl, nullptr, nullptr, nullptr, tab, TOK, DMODEL, DMODEL);
  k_gemm_split<1><<<dim3(TOK/128, DMODEL/128), blk, 0, stream>>>(xnh, xnl, wvTh, wvTl, vh, vl, nullptr, nullptr, nullptr, nullptr, TOK, DMODEL, DMODEL);
  k_vtrans<<<dim3(SEQ/32, 2, BATCH*NHEAD), blk, 0, stream>>>(vh, vl, vth, vtl);
  k_flash<<<dim3(SEQ/64, BATCH*NHEAD), blk, 0, stream>>>(qh, ql, kh, kl, vth, vtl, aoh, aol);
  k_gemm_split<2><<<dim3(TOK/128, DMODEL/128), blk, 0, stream>>>(aoh, aol, woTh, woTl, nullptr, nullptr, hb, out, x, nullptr, TOK, DMODEL, DMODEL);
  // router + sparse MoE
  k_router<<<dim3(TOK/4), blk, 0, stream>>>(hb, fnw, rw, gates, choice);
  k_build<<<dim3(TOK/256), blk, 0, stream>>>(choice, cnt, perm);
  k_prefix<<<dim3(1), dim3(64), 0, stream>>>(cnt, baseP);
  k_rmsnorm_bf<<<dim3(TOK/4), blk, 0, stream>>>(hb, fnw, hnb);
  k_moe1<<<dim3(TOK/128, DFF/128, NEXP), blk, 0, stream>>>(hnb, w1T, hmid, perm, cnt, baseP);
  k_moe2<<<dim3(TOK/128, DMODEL/128, NEXP), blk, 0, stream>>>(hmid, w2T, out, perm, cnt, baseP, gates);
}

// Round 5
// 672.668 us; speedup vs baseline: 1.1309x; 1.1309x over previous
//
#include <hip/hip_runtime.h>

#define BATCH 4
#define SEQ 2048
#define DMODEL 512
#define NHEAD 8
#define DHEAD 64
#define NEXP 8
#define DFF 2048
#define TOK (BATCH*SEQ)

typedef __attribute__((ext_vector_type(8))) short short8;
typedef __attribute__((ext_vector_type(8))) _Float16 half8;
typedef __attribute__((ext_vector_type(4))) float f32x4;
typedef unsigned short u16;

typedef const __attribute__((address_space(1))) void gvoid;
typedef __attribute__((address_space(3))) void lvoid;
__device__ __forceinline__ void gload16(const void* g, void* l){
  __builtin_amdgcn_global_load_lds((gvoid*)g, (lvoid*)l, 16, 0, 0);
}

__device__ inline f32x4 zero4(){ f32x4 z = {0.f,0.f,0.f,0.f}; return z; }
__device__ inline u16 f2bf(float f){ unsigned u; __builtin_memcpy(&u,&f,4); u = (u + 0x7fffu + ((u>>16)&1u)) >> 16; return (u16)u; }
__device__ inline unsigned pack2(_Float16 a, _Float16 b){
  unsigned short ua, ub; __builtin_memcpy(&ua,&a,2); __builtin_memcpy(&ub,&b,2);
  return (unsigned)ua | ((unsigned)ub<<16);
}

// ---------------- transpose + cast: W (R x C, f32) -> Wt (C x R) ----------------
__global__ __launch_bounds__(256) void k_tc_bf(const float* __restrict__ W, u16* __restrict__ Wt, int R, int C){
  __shared__ float tile[32][33];
  long e = blockIdx.z;
  const float* Wp = W + e*(long)R*C;
  u16* Op = Wt + e*(long)R*C;
  int c0 = blockIdx.x*32, r0 = blockIdx.y*32;
  int tx = threadIdx.x & 31, ty = threadIdx.x >> 5;
  #pragma unroll
  for (int i=0;i<4;i++){ int r = ty*4+i; tile[r][tx] = Wp[(long)(r0+r)*C + c0+tx]; }
  __syncthreads();
  #pragma unroll
  for (int i=0;i<4;i++){ int cc = ty*4+i; Op[(long)(c0+cc)*R + r0+tx] = f2bf(tile[tx][cc]); }
}

__global__ __launch_bounds__(256) void k_tc_split(const float* __restrict__ W, _Float16* __restrict__ H, _Float16* __restrict__ L, int R, int C){
  __shared__ float tile[32][33];
  int c0 = blockIdx.x*32, r0 = blockIdx.y*32;
  int tx = threadIdx.x & 31, ty = threadIdx.x >> 5;
  #pragma unroll
  for (int i=0;i<4;i++){ int r = ty*4+i; tile[r][tx] = W[(long)(r0+r)*C + c0+tx]; }
  __syncthreads();
  #pragma unroll
  for (int i=0;i<4;i++){
    int cc = ty*4+i;
    float v = tile[tx][cc];
    _Float16 hi = (_Float16)v;
    long o = (long)(c0+cc)*R + r0+tx;
    H[o] = hi; L[o] = (_Float16)(v - (float)hi);
  }
}

// ---------------- V transpose per head: vt[bh][d][s] = v[b][s][h*64+d] ----------------
__global__ __launch_bounds__(256) void k_vtrans(const _Float16* __restrict__ vh, const _Float16* __restrict__ vl,
                                                _Float16* __restrict__ vth, _Float16* __restrict__ vtl){
  __shared__ _Float16 t[32][33];
  int bh = blockIdx.z;
  int b = bh>>3, h = bh&7;
  int s0 = blockIdx.x*32, d0 = blockIdx.y*32;
  int tx = threadIdx.x & 31, ty = threadIdx.x >> 5;
  const _Float16* src = vh; _Float16* dst = vth;
  #pragma unroll
  for (int pass=0; pass<2; pass++){
    #pragma unroll
    for (int i=0;i<4;i++){
      int sl = ty*4+i;
      t[sl][tx] = src[((long)b*SEQ + s0+sl)*DMODEL + h*64 + d0 + tx];
    }
    __syncthreads();
    #pragma unroll
    for (int i=0;i<4;i++){
      int dl = ty*4+i;
      dst[((long)bh*64 + d0+dl)*SEQ + s0 + tx] = t[tx][dl];
    }
    __syncthreads();
    src = vl; dst = vtl;
  }
}

// ---------------- RMSNorm ----------------
__global__ __launch_bounds__(256) void k_rmsnorm_split(const float* __restrict__ x, const float* __restrict__ w,
                                                       _Float16* __restrict__ oh, _Float16* __restrict__ ol){
  int row = blockIdx.x*4 + (threadIdx.x>>6);
  int lane = threadIdx.x & 63;
  const float4* xr = (const float4*)(x + (long)row*DMODEL);
  float4 a = xr[lane*2], b = xr[lane*2+1];
  float ss = a.x*a.x+a.y*a.y+a.z*a.z+a.w*a.w + b.x*b.x+b.y*b.y+b.z*b.z+b.w*b.w;
  #pragma unroll
  for (int o=32;o;o>>=1) ss += __shfl_xor(ss, o);
  float sc = rsqrtf(ss*(1.0f/DMODEL) + 1e-5f);
  const float4* wr = (const float4*)w;
  float4 wa = wr[lane*2], wb = wr[lane*2+1];
  float v[8] = {a.x*sc*wa.x, a.y*sc*wa.y, a.z*sc*wa.z, a.w*sc*wa.w,
                b.x*sc*wb.x, b.y*sc*wb.y, b.z*sc*wb.z, b.w*sc*wb.w};
  half8 hv, lv;
  #pragma unroll
  for (int j=0;j<8;j++){ _Float16 hi = (_Float16)v[j]; hv[j] = hi; lv[j] = (_Float16)(v[j]-(float)hi); }
  long off = (long)row*DMODEL + lane*8;
  *(half8*)(oh + off) = hv;
  *(half8*)(ol + off) = lv;
}

__global__ __launch_bounds__(256) void k_rmsnorm_bf(const float* __restrict__ x, const float* __restrict__ w, u16* __restrict__ o){
  int row = blockIdx.x*4 + (threadIdx.x>>6);
  int lane = threadIdx.x & 63;
  const float4* xr = (const float4*)(x + (long)row*DMODEL);
  float4 a = xr[lane*2], b = xr[lane*2+1];
  float ss = a.x*a.x+a.y*a.y+a.z*a.z+a.w*a.w + b.x*b.x+b.y*b.y+b.z*b.z+b.w*b.w;
  #pragma unroll
  for (int ofs=32;ofs;ofs>>=1) ss += __shfl_xor(ss, ofs);
  float sc = rsqrtf(ss*(1.0f/DMODEL) + 1e-5f);
  const float4* wr = (const float4*)w;
  float4 wa = wr[lane*2], wb = wr[lane*2+1];
  short8 ov;
  ov[0]=(short)f2bf(a.x*sc*wa.x); ov[1]=(short)f2bf(a.y*sc*wa.y);
  ov[2]=(short)f2bf(a.z*sc*wa.z); ov[3]=(short)f2bf(a.w*sc*wa.w);
  ov[4]=(short)f2bf(b.x*sc*wb.x); ov[5]=(short)f2bf(b.y*sc*wb.y);
  ov[6]=(short)f2bf(b.z*sc*wb.z); ov[7]=(short)f2bf(b.w*sc*wb.w);
  *(short8*)(o + (long)row*DMODEL + lane*8) = ov;
}

// ---------------- RoPE cos/sin table ----------------
__global__ __launch_bounds__(256) void k_rope_tab(float2* __restrict__ tab){
  int idx = blockIdx.x*256 + threadIdx.x;
  int s = idx>>5, i = idx&31;
  float invf = powf(10000.0f, -(float)(2*i)*(1.0f/64.0f));
  float ang = (float)s * invf;
  tab[idx] = make_float2(cosf(ang), sinf(ang));
}

// ---------------- split-f16 GEMM (fp32 fidelity), gload_lds + 2-phase dbuf ----------------
template<int EPI>
__global__ __launch_bounds__(256) void k_gemm_split(
    const _Float16* __restrict__ Ah, const _Float16* __restrict__ Al,
    const _Float16* __restrict__ Bh, const _Float16* __restrict__ Bl,
    _Float16* __restrict__ oh, _Float16* __restrict__ ol,
    float* __restrict__ of1, float* __restrict__ of2,
    const float* __restrict__ extra, const float2* __restrict__ tab,
    int M, int N, int K)
{
  __shared__ _Float16 lAb[2*128*64];
  __shared__ _Float16 lBb[2*128*64];
  const int mb = blockIdx.x*128, nb = blockIdx.y*128;
  const int tid = threadIdx.x, lane = tid&63, wv = tid>>6;
  const int wr = wv>>1, wc = wv&1;
  const int fr = lane&15, fq = lane>>4;
  const int cs = (lane&7) ^ (lane>>3);
  const _Float16* pA[4]; const _Float16* pB[4];
  #pragma unroll
  for (int i=0;i<4;i++){
    int rr = i*32 + wv*8 + (lane>>3);
    const _Float16* a = (cs<4)? Ah : Al;
    const _Float16* b = (cs<4)? Bh : Bl;
    pA[i] = a + (long)(mb+rr)*K + (cs&3)*8;
    pB[i] = b + (long)(nb+rr)*K + (cs&3)*8;
  }
  f32x4 acc[4][4];
  #pragma unroll
  for (int mi=0;mi<4;mi++)
    #pragma unroll
    for (int ni=0;ni<4;ni++) acc[mi][ni] = zero4();

  #pragma unroll
  for (int i=0;i<4;i++){
    gload16(pA[i], (char*)lAb + (i*32+wv*8)*128);
    gload16(pB[i], (char*)lBb + (i*32+wv*8)*128);
  }
  __syncthreads();
  const int NT = K>>5;
  int cur = 0;
  for (int t=0; t<NT; ++t){
    if (t+1 < NT){
      int k2 = (t+1)<<5;
      #pragma unroll
      for (int i=0;i<4;i++){
        int db = ((cur^1)<<14) + (i*32+wv*8)*128;
        gload16(pA[i]+k2, (char*)lAb + db);
        gload16(pB[i]+k2, (char*)lBb + db);
      }
    }
    const char* cA = (const char*)lAb + (cur<<14);
    const char* cB = (const char*)lBb + (cur<<14);
    half8 ax[4], ay[4], bx[4], by[4];
    #pragma unroll
    for (int mi=0;mi<4;mi++){
      int row = wr*64 + mi*16 + fr; int m7 = row&7; const char* rb = cA + row*128;
      ax[mi] = *(const half8*)(rb + (((fq  ) ^ m7)<<4));
      ay[mi] = *(const half8*)(rb + (((fq+4) ^ m7)<<4));
    }
    #pragma unroll
    for (int ni=0;ni<4;ni++){
      int row = wc*64 + ni*16 + fr; int m7 = row&7; const char* rb = cB + row*128;
      bx[ni] = *(const half8*)(rb + (((fq  ) ^ m7)<<4));
      by[ni] = *(const half8*)(rb + (((fq+4) ^ m7)<<4));
    }
    __builtin_amdgcn_s_setprio(1);
    #pragma unroll
    for (int mi=0;mi<4;mi++)
      #pragma unroll
      for (int ni=0;ni<4;ni++){
        acc[mi][ni] = __builtin_amdgcn_mfma_f32_16x16x32_f16(ax[mi], bx[ni], acc[mi][ni], 0,0,0);
        acc[mi][ni] = __builtin_amdgcn_mfma_f32_16x16x32_f16(ax[mi], by[ni], acc[mi][ni], 0,0,0);
        acc[mi][ni] = __builtin_amdgcn_mfma_f32_16x16x32_f16(ay[mi], bx[ni], acc[mi][ni], 0,0,0);
      }
    __builtin_amdgcn_s_setprio(0);
    __syncthreads();
    cur ^= 1;
  }
  #pragma unroll
  for (int mi=0;mi<4;mi++)
    #pragma unroll
    for (int ni=0;ni<4;ni++)
      #pragma unroll
      for (int r=0;r<4;r++){
        int row = mb + wr*64 + mi*16 + fq*4 + r;
        int col = nb + wc*64 + ni*16 + fr;
        long off = (long)row*N + col;
        float v = acc[mi][ni][r];
        if (EPI==0){
          float v2 = __shfl_xor(v, 1);
          float2 csn = tab[(row & (SEQ-1))*32 + ((col&63)>>1)];
          float o = (col&1) ? (v2*csn.y + v*csn.x) : (v*csn.x - v2*csn.y);
          _Float16 hi = (_Float16)o;
          oh[off] = hi; ol[off] = (_Float16)(o - (float)hi);
        } else if (EPI==1){
          _Float16 hi = (_Float16)v;
          oh[off] = hi; ol[off] = (_Float16)(v - (float)hi);
        } else {
          float hv = extra[off] + v;
          of1[off] = hv; of2[off] = hv;
        }
      }
}

// ---------------- split-f16 causal flash attention (paired qt + K/V prefetch pipeline) ----------------
__global__ __launch_bounds__(256) void k_flash(
    const _Float16* __restrict__ Qh, const _Float16* __restrict__ Ql,
    const _Float16* __restrict__ Kh, const _Float16* __restrict__ Kl,
    const _Float16* __restrict__ Vth, const _Float16* __restrict__ Vtl,
    _Float16* __restrict__ Oh, _Float16* __restrict__ Ol)
{
  __shared__ _Float16 lK[64*128];
  __shared__ _Float16 lV[64*128];
  __shared__ _Float16 lP[4*2304];
  const int pidx = blockIdx.x, bh = blockIdx.y;
  const int b = bh>>3, hh = bh&7;
  const int tid = threadIdx.x, lane = tid&63, wid = tid>>6;
  const int fr = lane&15, fq = lane>>4;
  const long base = ((long)b*SEQ)*DMODEL + hh*DHEAD;
  const long vtb  = (long)bh*DHEAD*SEQ;
  const int srow = tid>>4, sch = tid&15;
  const unsigned pw = wid*2304;
  const float SCL = 0.18033688011112042f;      // 0.125 * log2(e)

  half8 kreg[4], vreg[4];                      // in-flight K/V tile (T14 pipeline)
  const _Float16* ks = (sch<8) ? Kh : Kl;
  const _Float16* vs = (sch<8) ? Vth : Vtl;
  #pragma unroll
  for (int i=0;i<4;i++){                       // prefetch tile 0 of pass 0
    int row = i*16 + srow;
    kreg[i] = *(const half8*)(ks + base + (long)row*DMODEL + (sch&7)*8);
    vreg[i] = *(const half8*)(vs + vtb + (long)row*SEQ + (sch&7)*8);
  }

  for (int pass=0; pass<2; pass++){
    const int qt = pass ? (SEQ/64-1-pidx) : pidx;
    const int q0 = qt*64, qw = q0 + wid*16;
    half8 qfh[2], qfl[2];
    #pragma unroll
    for (int kk=0;kk<2;kk++){
      long o = base + (long)(qw+fr)*DMODEL + kk*32 + fq*8;
      qfh[kk] = *(const half8*)(Qh + o);
      qfl[kk] = *(const half8*)(Ql + o);
    }
    f32x4 oacc[4];
    #pragma unroll
    for (int i=0;i<4;i++) oacc[i] = zero4();
    float mrow[4], lrow[4];
    #pragma unroll
    for (int r=0;r<4;r++){ mrow[r] = -__builtin_inff(); lrow[r] = 0.f; }

    for (int kvt=0; kvt<=qt; kvt++){
      int k0 = kvt*64;
      __syncthreads();                         // all waves done reading prev tile's LDS
      #pragma unroll
      for (int i=0;i<4;i++){
        int row = i*16 + srow;
        int slot = ((sch ^ (row&15))<<4);
        *(half8*)((char*)lK + row*256 + slot) = kreg[i];
        *(half8*)((char*)lV + row*256 + slot) = vreg[i];
      }
      __syncthreads();
      // ---- issue next tile's global loads; latency hides under this tile's compute
      {
        int nk0 = -1;
        if (kvt < qt) nk0 = k0 + 64;
        else if (pass == 0) nk0 = 0;           // first tile of pass 1
        if (nk0 >= 0){
          #pragma unroll
          for (int i=0;i<4;i++){
            int row = i*16 + srow;
            kreg[i] = *(const half8*)(ks + base + (long)(nk0+row)*DMODEL + (sch&7)*8);
            vreg[i] = *(const half8*)(vs + vtb + (long)row*SEQ + nk0 + (sch&7)*8);
          }
        }
      }
      // ---- scores
      f32x4 sc[4];
      __builtin_amdgcn_s_setprio(1);
      #pragma unroll
      for (int ns=0;ns<4;ns++){
        f32x4 a = zero4();
        #pragma unroll
        for (int kk=0;kk<2;kk++){
          int row = ns*16 + fr; int m15 = row&15; const char* rb = (const char*)lK + row*256;
          half8 kfh = *(const half8*)(rb + (((kk*4+fq)   ^ m15)<<4));
          half8 kfl = *(const half8*)(rb + (((kk*4+fq+8) ^ m15)<<4));
          a = __builtin_amdgcn_mfma_f32_16x16x32_f16(qfh[kk], kfh, a, 0,0,0);
          a = __builtin_amdgcn_mfma_f32_16x16x32_f16(qfh[kk], kfl, a, 0,0,0);
          a = __builtin_amdgcn_mfma_f32_16x16x32_f16(qfl[kk], kfh, a, 0,0,0);
        }
        sc[ns] = a;
      }
      __builtin_amdgcn_s_setprio(0);
      // ---- scale to exp2 base; mask only on diagonal tile
      float pmax[4];
      #pragma unroll
      for (int r=0;r<4;r++) pmax[r] = -__builtin_inff();
      if (kvt == qt){
        #pragma unroll
        for (int ns=0;ns<4;ns++)
          #pragma unroll
          for (int r=0;r<4;r++){
            int kvp = k0 + ns*16 + fr;
            int qp  = qw + fq*4 + r;
            float s = sc[ns][r]*SCL;
            if (kvp > qp) s = -1e30f;
            sc[ns][r] = s;
            pmax[r] = fmaxf(pmax[r], s);
          }
      } else {
        #pragma unroll
        for (int ns=0;ns<4;ns++)
          #pragma unroll
          for (int r=0;r<4;r++){
            float s = sc[ns][r]*SCL;
            sc[ns][r] = s;
            pmax[r] = fmaxf(pmax[r], s);
          }
      }
      #pragma unroll
      for (int o=1;o<16;o<<=1)
        #pragma unroll
        for (int r=0;r<4;r++) pmax[r] = fmaxf(pmax[r], __shfl_xor(pmax[r], o));
      // ---- defer-max rescale
      bool need = false;
      #pragma unroll
      for (int r=0;r<4;r++) need = need || (pmax[r] > mrow[r] + 10.f);
      if (__any(need)){
        float sf[4];
        #pragma unroll
        for (int r=0;r<4;r++){
          float mn = fmaxf(mrow[r], pmax[r]);
          sf[r] = exp2f(mrow[r]-mn);
          mrow[r] = mn;
          lrow[r] *= sf[r];
        }
        #pragma unroll
        for (int dt=0;dt<4;dt++)
          #pragma unroll
          for (int r=0;r<4;r++) oacc[dt][r] *= sf[r];
      }
      // ---- exp2 + P pair-store
      float rsum[4] = {0,0,0,0};
      #pragma unroll
      for (int ns=0;ns<4;ns++)
        #pragma unroll
        for (int r=0;r<4;r++){
          float pv = exp2f(sc[ns][r]-mrow[r]);
          rsum[r] += pv;
          float pv2 = __shfl_xor(pv, 1);
          float e0 = (fr&1)? pv2 : pv;
          float e1 = (fr&1)? pv : pv2;
          _Float16 f0 = (_Float16)e0, f1 = (_Float16)e1;
          unsigned word;
          if (fr&1) word = pack2((_Float16)(e0-(float)f0), (_Float16)(e1-(float)f1));
          else      word = pack2(f0, f1);
          unsigned eo = pw + ((fr&1)? 1152u:0u) + (unsigned)((fq*4+r)*72 + ns*16 + (fr&~1));
          *(unsigned*)((char*)lP + eo*2) = word;
        }
      #pragma unroll
      for (int o=1;o<16;o<<=1)
        #pragma unroll
        for (int r=0;r<4;r++) rsum[r] += __shfl_xor(rsum[r], o);
      #pragma unroll
      for (int r=0;r<4;r++) lrow[r] += rsum[r];
      // ---- PV (wave-local P; no barrier needed)
      __builtin_amdgcn_s_setprio(1);
      #pragma unroll
      for (int kk=0;kk<2;kk++){
        const char* pb = (const char*)lP + (pw + (unsigned)(fr*72 + kk*32))*2;
        half8 pfh = *(const half8*)(pb + fq*16);
        half8 pfl = *(const half8*)(pb + 2304 + fq*16);
        #pragma unroll
        for (int dt=0;dt<4;dt++){
          int row = dt*16 + fr; int m15 = row&15; const char* vb = (const char*)lV + row*256;
          half8 vfh = *(const half8*)(vb + (((kk*4+fq)   ^ m15)<<4));
          half8 vfl = *(const half8*)(vb + (((kk*4+fq+8) ^ m15)<<4));
          oacc[dt] = __builtin_amdgcn_mfma_f32_16x16x32_f16(pfh, vfh, oacc[dt], 0,0,0);
          oacc[dt] = __builtin_amdgcn_mfma_f32_16x16x32_f16(pfh, vfl, oacc[dt], 0,0,0);
          oacc[dt] = __builtin_amdgcn_mfma_f32_16x16x32_f16(pfl, vfh, oacc[dt], 0,0,0);
        }
      }
      __builtin_amdgcn_s_setprio(0);
    }
    #pragma unroll
    for (int dt=0;dt<4;dt++)
      #pragma unroll
      for (int r=0;r<4;r++){
        int qp = qw + fq*4 + r;
        float ov = oacc[dt][r] / lrow[r];
        long o = base + (long)qp*DMODEL + dt*16 + fr;
        _Float16 hi = (_Float16)ov;
        Oh[o] = hi; Ol[o] = (_Float16)(ov - (float)hi);
      }
  }
}

// ---------------- router: fp32 RMSNorm + logits + softmax + top2 (no atomics) ----------------
__global__ __launch_bounds__(256) void k_router(const float* __restrict__ h, const float* __restrict__ w,
                                                const float* __restrict__ rw, float* __restrict__ gates,
                                                unsigned* __restrict__ choice){
  int tok = blockIdx.x*4 + (threadIdx.x>>6);
  int lane = threadIdx.x & 63;
  const float4* xr = (const float4*)(h + (long)tok*DMODEL);
  float4 a = xr[lane*2], b = xr[lane*2+1];
  float ss = a.x*a.x+a.y*a.y+a.z*a.z+a.w*a.w + b.x*b.x+b.y*b.y+b.z*b.z+b.w*b.w;
  #pragma unroll
  for (int o=32;o;o>>=1) ss += __shfl_xor(ss, o);
  float sc = rsqrtf(ss*(1.0f/DMODEL) + 1e-5f);
  const float4* wr = (const float4*)w;
  float4 wa = wr[lane*2], wb = wr[lane*2+1];
  float xv[8] = {a.x*sc*wa.x, a.y*sc*wa.y, a.z*sc*wa.z, a.w*sc*wa.w,
                 b.x*sc*wb.x, b.y*sc*wb.y, b.z*sc*wb.z, b.w*sc*wb.w};
  float lg[8] = {0,0,0,0,0,0,0,0};
  #pragma unroll
  for (int j=0;j<8;j++){
    const float* rp = rw + (long)(lane*8+j)*NEXP;
    #pragma unroll
    for (int e=0;e<8;e++) lg[e] += xv[j]*rp[e];
  }
  #pragma unroll
  for (int o=1;o<64;o<<=1)
    #pragma unroll
    for (int e=0;e<8;e++) lg[e] += __shfl_xor(lg[e], o);
  float mx = lg[0];
  #pragma unroll
  for (int e=1;e<8;e++) mx = fmaxf(mx, lg[e]);
  float pe[8], sm = 0.f;
  #pragma unroll
  for (int e=0;e<8;e++){ pe[e] = expf(lg[e]-mx); sm += pe[e]; }
  #pragma unroll
  for (int e=0;e<8;e++) pe[e] /= sm;
  int e1 = 0; float p1 = pe[0];
  #pragma unroll
  for (int e=1;e<8;e++) if (pe[e] > p1){ p1 = pe[e]; e1 = e; }
  int e2 = -1; float p2 = -1.f;
  #pragma unroll
  for (int e=0;e<8;e++) if (e != e1 && pe[e] > p2){ p2 = pe[e]; e2 = e; }
  float gs = p1 + p2;
  if (lane == 0){
    #pragma unroll
    for (int e=0;e<8;e++)
      gates[(long)tok*NEXP + e] = (e==e1) ? (p1/gs) : ((e==e2) ? (p2/gs) : 0.f);
    choice[tok] = (unsigned)e1 | ((unsigned)e2<<8);
  }
}

// ---------------- build expert lists: block-local counting sort ----------------
__global__ __launch_bounds__(256) void k_build(const unsigned* __restrict__ choice,
                                               int* __restrict__ cnt, int* __restrict__ perm){
  __shared__ int lcnt[NEXP];
  __shared__ int lbase[NEXP];
  const int tid = threadIdx.x;
  const int tok = blockIdx.x*256 + tid;
  if (tid < NEXP) lcnt[tid] = 0;
  __syncthreads();
  unsigned ch = choice[tok];
  int e1 = ch & 0xff, e2 = (ch>>8) & 0xff;
  int p1 = atomicAdd(&lcnt[e1], 1);
  int p2 = atomicAdd(&lcnt[e2], 1);
  __syncthreads();
  if (tid < NEXP) lbase[tid] = atomicAdd(&cnt[tid], lcnt[tid]);
  __syncthreads();
  perm[e1*TOK + lbase[e1] + p1] = tok;
  perm[e2*TOK + lbase[e2] + p2] = tok;
}

__global__ void k_prefix(const int* __restrict__ cnt, int* __restrict__ baseP){
  if (threadIdx.x==0 && blockIdx.x==0){
    int run = 0;
    for (int e=0;e<NEXP;e++){ baseP[e] = run; run += (cnt[e]+127) & ~127; }
  }
}

// ---------------- sparse MoE layer 1: gathered A via gload_lds, GELU -> compact mid ----------------
__global__ __launch_bounds__(256) void k_moe1(
    const u16* __restrict__ A, const u16* __restrict__ W1, u16* __restrict__ mid,
    const int* __restrict__ perm, const int* __restrict__ cnt, const int* __restrict__ baseP)
{
  const int e = blockIdx.z;
  const int ce = cnt[e];
  const int mb = blockIdx.x*128;
  if (mb >= ce) return;
  const int bp = baseP[e];
  const u16* Bt = W1 + (size_t)e*DFF*DMODEL;
  const int nb = blockIdx.y*128;
  __shared__ u16 lA[128*64];
  __shared__ u16 lB[128*64];
  const int tid = threadIdx.x, lane = tid&63, wv = tid>>6;
  const int wr = wv>>1, wc = wv&1;
  const int fr = lane&15, fq = lane>>4;
  const int cs = (lane&7) ^ (lane>>3);
  const u16* pA[4]; const u16* pB[4];
  #pragma unroll
  for (int i=0;i<4;i++){
    int rr = mb + i*32 + wv*8 + (lane>>3);
    int tok = perm[e*TOK + (rr < ce ? rr : ce-1)];
    pA[i] = A  + (long)tok*DMODEL + cs*8;
    pB[i] = Bt + (long)(nb + i*32 + wv*8 + (lane>>3))*DMODEL + cs*8;
  }
  f32x4 acc[4][4];
  #pragma unroll
  for (int mi=0;mi<4;mi++)
    #pragma unroll
    for (int ni=0;ni<4;ni++) acc[mi][ni] = zero4();

  for (int kt=0; kt<DMODEL; kt+=64){
    #pragma unroll
    for (int i=0;i<4;i++){
      gload16(pA[i]+kt, (char*)lA + (i*32+wv*8)*128);
      gload16(pB[i]+kt, (char*)lB + (i*32+wv*8)*128);
    }
    __syncthreads();
    __builtin_amdgcn_s_setprio(1);
    #pragma unroll
    for (int kk=0;kk<2;kk++){
      short8 af[4], bff[4];
      #pragma unroll
      for (int mi=0;mi<4;mi++){
        int row = wr*64 + mi*16 + fr;
        af[mi] = *(const short8*)((char*)lA + row*128 + (((kk*4+fq) ^ (row&7))<<4));
      }
      #pragma unroll
      for (int ni=0;ni<4;ni++){
        int row = wc*64 + ni*16 + fr;
        bff[ni] = *(const short8*)((char*)lB + row*128 + (((kk*4+fq) ^ (row&7))<<4));
      }
      #pragma unroll
      for (int mi=0;mi<4;mi++)
        #pragma unroll
        for (int ni=0;ni<4;ni++)
          acc[mi][ni] = __builtin_amdgcn_mfma_f32_16x16x32_bf16(af[mi], bff[ni], acc[mi][ni], 0,0,0);
    }
    __builtin_amdgcn_s_setprio(0);
    __syncthreads();
  }
  #pragma unroll
  for (int mi=0;mi<4;mi++)
    #pragma unroll
    for (int ni=0;ni<4;ni++)
      #pragma unroll
      for (int r=0;r<4;r++){
        int row_loc = mb + wr*64 + mi*16 + fq*4 + r;
        int col = nb + wc*64 + ni*16 + fr;
        float v = acc[mi][ni][r];
        mid[(size_t)(bp + row_loc)*DFF + col] = f2bf(0.5f*v*(1.f + erff(v*0.7071067811865475f)));
      }
}

// ---------------- sparse MoE layer 2: gload_lds, gated atomic scatter ----------------
__global__ __launch_bounds__(256) void k_moe2(
    const u16* __restrict__ mid, const u16* __restrict__ W2, float* __restrict__ out,
    const int* __restrict__ perm, const int* __restrict__ cnt, const int* __restrict__ baseP,
    const float* __restrict__ gates)
{
  const int e = blockIdx.z;
  const int ce = cnt[e];
  const int mb = blockIdx.x*128;
  if (mb >= ce) return;
  const int bp = baseP[e];
  const u16* Bt = W2 + (size_t)e*DMODEL*DFF;
  const int nb = blockIdx.y*128;
  __shared__ u16 lA[128*64];
  __shared__ u16 lB[128*64];
  const int tid = threadIdx.x, lane = tid&63, wv = tid>>6;
  const int wr = wv>>1, wc = wv&1;
  const int fr = lane&15, fq = lane>>4;
  const int cs = (lane&7) ^ (lane>>3);
  const u16* pA[4]; const u16* pB[4];
  #pragma unroll
  for (int i=0;i<4;i++){
    int rr = i*32 + wv*8 + (lane>>3);
    pA[i] = mid + (size_t)(bp + mb + rr)*DFF + cs*8;
    pB[i] = Bt  + (long)(nb + rr)*DFF + cs*8;
  }
  f32x4 acc[4][4];
  #pragma unroll
  for (int mi=0;mi<4;mi++)
    #pragma unroll
    for (int ni=0;ni<4;ni++) acc[mi][ni] = zero4();

  for (int kt=0; kt<DFF; kt+=64){
    #pragma unroll
    for (int i=0;i<4;i++){
      gload16(pA[i]+kt, (char*)lA + (i*32+wv*8)*128);
      gload16(pB[i]+kt, (char*)lB + (i*32+wv*8)*128);
    }
    __syncthreads();
    __builtin_amdgcn_s_setprio(1);
    #pragma unroll
    for (int kk=0;kk<2;kk++){
      short8 af[4], bff[4];
      #pragma unroll
      for (int mi=0;mi<4;mi++){
        int row = wr*64 + mi*16 + fr;
        af[mi] = *(const short8*)((char*)lA + row*128 + (((kk*4+fq) ^ (row&7))<<4));
      }
      #pragma unroll
      for (int ni=0;ni<4;ni++){
        int row = wc*64 + ni*16 + fr;
        bff[ni] = *(const short8*)((char*)lB + row*128 + (((kk*4+fq) ^ (row&7))<<4));
      }
      #pragma unroll
      for (int mi=0;mi<4;mi++)
        #pragma unroll
        for (int ni=0;ni<4;ni++)
          acc[mi][ni] = __builtin_amdgcn_mfma_f32_16x16x32_bf16(af[mi], bff[ni], acc[mi][ni], 0,0,0);
    }
    __builtin_amdgcn_s_setprio(0);
    __syncthreads();
  }
  #pragma unroll
  for (int mi=0;mi<4;mi++)
    #pragma unroll
    for (int ni=0;ni<4;ni++)
      #pragma unroll
      for (int r=0;r<4;r++){
        int row_loc = mb + wr*64 + mi*16 + fq*4 + r;
        if (row_loc < ce){
          int tok = perm[e*TOK + row_loc];
          int col = nb + wc*64 + ni*16 + fr;
          float g = gates[(long)tok*NEXP + e];
          atomicAdd(out + (long)tok*DMODEL + col, g*acc[mi][ni][r]);
        }
      }
}

// ---------------- launch ----------------
extern "C" void kernel_launch(void* const* d_in, const int* in_sizes, int n_in,
                              void* d_out, int out_size, void* d_ws, size_t ws_size,
                              hipStream_t stream)
{
  const float* x   = (const float*)d_in[0];
  const float* anw = (const float*)d_in[1];
  const float* wq  = (const float*)d_in[2];
  const float* wk  = (const float*)d_in[3];
  const float* wv  = (const float*)d_in[4];
  const float* wo  = (const float*)d_in[5];
  const float* fnw = (const float*)d_in[6];
  const float* rw  = (const float*)d_in[7];
  const float* w1  = (const float*)d_in[8];
  const float* w2  = (const float*)d_in[9];
  float* out = (float*)d_out;

  char* p = (char*)d_ws;
  auto alloc = [&](size_t n){ char* r = p; p += (n + 255) & ~(size_t)255; return r; };
  // region A (80MB): dead after flash; reused as compact MoE mid buffer (68MB needed)
  _Float16* xnh = (_Float16*)alloc((size_t)TOK*DMODEL*2);
  _Float16* xnl = (_Float16*)alloc((size_t)TOK*DMODEL*2);
  _Float16* qh  = (_Float16*)alloc((size_t)TOK*DMODEL*2);
  _Float16* ql  = (_Float16*)alloc((size_t)TOK*DMODEL*2);
  _Float16* kh  = (_Float16*)alloc((size_t)TOK*DMODEL*2);
  _Float16* kl  = (_Float16*)alloc((size_t)TOK*DMODEL*2);
  _Float16* vh  = (_Float16*)alloc((size_t)TOK*DMODEL*2);
  _Float16* vl  = (_Float16*)alloc((size_t)TOK*DMODEL*2);
  _Float16* vth = (_Float16*)alloc((size_t)TOK*DMODEL*2);
  _Float16* vtl = (_Float16*)alloc((size_t)TOK*DMODEL*2);
  u16* hmid = (u16*)xnh;   // alias region A
  // persistent
  _Float16* wqTh = (_Float16*)alloc((size_t)DMODEL*DMODEL*2);
  _Float16* wqTl = (_Float16*)alloc((size_t)DMODEL*DMODEL*2);
  _Float16* wkTh = (_Float16*)alloc((size_t)DMODEL*DMODEL*2);
  _Float16* wkTl = (_Float16*)alloc((size_t)DMODEL*DMODEL*2);
  _Float16* wvTh = (_Float16*)alloc((size_t)DMODEL*DMODEL*2);
  _Float16* wvTl = (_Float16*)alloc((size_t)DMODEL*DMODEL*2);
  _Float16* woTh = (_Float16*)alloc((size_t)DMODEL*DMODEL*2);
  _Float16* woTl = (_Float16*)alloc((size_t)DMODEL*DMODEL*2);
  u16* w1T = (u16*)alloc((size_t)NEXP*DFF*DMODEL*2);
  u16* w2T = (u16*)alloc((size_t)NEXP*DMODEL*DFF*2);
  _Float16* aoh = (_Float16*)alloc((size_t)TOK*DMODEL*2);
  _Float16* aol = (_Float16*)alloc((size_t)TOK*DMODEL*2);
  float* hb  = (float*)alloc((size_t)TOK*DMODEL*4);
  u16* hnb   = (u16*)alloc((size_t)TOK*DMODEL*2);
  float2* tab = (float2*)alloc((size_t)SEQ*32*sizeof(float2));
  float* gates = (float*)alloc((size_t)TOK*NEXP*4);
  int* perm  = (int*)alloc((size_t)NEXP*TOK*4);
  unsigned* choice = (unsigned*)alloc((size_t)TOK*4);
  int* cnt   = (int*)alloc(64*4);
  int* baseP = (int*)alloc(64*4);

  dim3 blk(256);
  hipMemsetAsync(cnt, 0, NEXP*sizeof(int), stream);
  // weight prep
  k_tc_split<<<dim3(16,16,1), blk, 0, stream>>>(wq, wqTh, wqTl, DMODEL, DMODEL);
  k_tc_split<<<dim3(16,16,1), blk, 0, stream>>>(wk, wkTh, wkTl, DMODEL, DMODEL);
  k_tc_split<<<dim3(16,16,1), blk, 0, stream>>>(wv, wvTh, wvTl, DMODEL, DMODEL);
  k_tc_split<<<dim3(16,16,1), blk, 0, stream>>>(wo, woTh, woTl, DMODEL, DMODEL);
  k_tc_bf<<<dim3(DFF/32, DMODEL/32, NEXP), blk, 0, stream>>>(w1, w1T, DMODEL, DFF);
  k_tc_bf<<<dim3(DMODEL/32, DFF/32, NEXP), blk, 0, stream>>>(w2, w2T, DFF, DMODEL);
  k_rope_tab<<<dim3(SEQ*32/256), blk, 0, stream>>>(tab);
  // attention path (split f16)
  k_rmsnorm_split<<<dim3(TOK/4), blk, 0, stream>>>(x, anw, xnh, xnl);
  k_gemm_split<0><<<dim3(TOK/128, DMODEL/128), blk, 0, stream>>>(xnh, xnl, wqTh, wqTl, qh, ql, nullptr, nullptr, nullptr, tab, TOK, DMODEL, DMODEL);
  k_gemm_split<0><<<dim3(TOK/128, DMODEL/128), blk, 0, stream>>>(xnh, xnl, wkTh, wkTl, kh, kl, nullptr, nullptr, nullptr, tab, TOK, DMODEL, DMODEL);
  k_gemm_split<1><<<dim3(TOK/128, DMODEL/128), blk, 0, stream>>>(xnh, xnl, wvTh, wvTl, vh, vl, nullptr, nullptr, nullptr, nullptr, TOK, DMODEL, DMODEL);
  k_vtrans<<<dim3(SEQ/32, 2, BATCH*NHEAD), blk, 0, stream>>>(vh, vl, vth, vtl);
  k_flash<<<dim3(SEQ/128, BATCH*NHEAD), blk, 0, stream>>>(qh, ql, kh, kl, vth, vtl, aoh, aol);
  k_gemm_split<2><<<dim3(TOK/128, DMODEL/128), blk, 0, stream>>>(aoh, aol, woTh, woTl, nullptr, nullptr, hb, out, x, nullptr, TOK, DMODEL, DMODEL);
  // router + sparse MoE
  k_router<<<dim3(TOK/4), blk, 0, stream>>>(hb, fnw, rw, gates, choice);
  k_build<<<dim3(TOK/256), blk, 0, stream>>>(choice, cnt, perm);
  k_prefix<<<dim3(1), dim3(64), 0, stream>>>(cnt, baseP);
  k_rmsnorm_bf<<<dim3(TOK/4), blk, 0, stream>>>(hb, fnw, hnb);
  k_moe1<<<dim3(TOK/128, DFF/128, NEXP), blk, 0, stream>>>(hnb, w1T, hmid, perm, cnt, baseP);
  k_moe2<<<dim3(TOK/128, DMODEL/128, NEXP), blk, 0, stream>>>(hmid, w2T, out, perm, cnt, baseP, gates);
}